// Round 1
// baseline (18932.304 us; speedup 1.0000x reference)
//
#include <hip/hip_runtime.h>
#include <hip/hip_bf16.h>

typedef __attribute__((ext_vector_type(8))) short v8s;
typedef __attribute__((ext_vector_type(4))) float v4f;

constexpr int T_  = 512;
constexpr int RS  = 65536;   // fp32 row stride of enc/dec/out: T*D
constexpr int AST = 392;     // Abuf row stride in shorts (384 cols + 8 pad)

// ws offsets (bytes)
constexpr size_t OFF_WL0  = 0;         // enc L0 [eW0;eU0] frag-packed bf16, 786432 sh
constexpr size_t OFF_WL1  = 1572864;   // enc L1 (W1+U1) frag-packed bf16, 262144 sh
constexpr size_t OFF_WDEC = 2097152;   // dec (dU + oW@dW) frag-packed bf16, 262144 sh
constexpr size_t OFF_WOUT = 2621440;   // oW frag-packed bf16, 32768 sh
constexpr size_t OFF_BDR  = 2686976;   // db + ob@dW, 1024 f32
constexpr size_t OFF_HBUF = 2691072;   // h exchange [32 grp][2 parity][16 row][256 j] bf16
constexpr size_t OFF_FLAG = 3215360;   // [32 grp][4 chunk] u32 flags @128B stride
// total 3231744 bytes

__device__ __forceinline__ unsigned short f2b(float x) {
    __hip_bfloat16 h = __float2bfloat16(x);
    return *(unsigned short*)&h;
}
__device__ __forceinline__ float sig(float x) { return 1.f / (1.f + __expf(-x)); }

// ---------------- prep: repack fp32 weights into per-(chunk,wave,gate) -----
// frag-linear bf16.  Frag layout (16x16x32): lane l, elem e of frag (g,kt)
// holds B[k = kt*32 + (l>>4)*8 + e][n = g*256 + c*64 + w*16 + (l&15)].
// Gate-PLANAR (natural) column order: n = gate*256 + j.
__global__ void __launch_bounds__(256) prep_kernel(
    const float* __restrict__ eW0, const float* __restrict__ eU0,
    const float* __restrict__ eW1, const float* __restrict__ eU1,
    const float* __restrict__ dW,  const float* __restrict__ dU,
    const float* __restrict__ db,
    const float* __restrict__ oW,  const float* __restrict__ ob,
    char* __restrict__ ws)
{
    const unsigned gid = blockIdx.x * 256u + threadIdx.x;

    if (gid < 786432u) {                       // WL0 = [eW0;eU0], KT=12
        const unsigned fid = gid;
        const int e = fid & 7, l = (fid >> 3) & 63;
        const int rest = fid >> 9;             // 0..767
        const int kt = rest % 12, q = rest / 12;
        const int g = q & 3, w2 = (q >> 2) & 3, c2 = q >> 4;
        const int k = kt * 32 + (l >> 4) * 8 + e;
        const int n = g * 256 + c2 * 64 + w2 * 16 + (l & 15);
        const float v = (k < 128) ? eW0[(size_t)k * 1024 + n]
                                  : eU0[(size_t)(k - 128) * 1024 + n];
        ((unsigned short*)(ws + OFF_WL0))[fid] = f2b(v);
    } else if (gid < 1048576u) {               // WL1 = W1+U1, KT=8
        const unsigned fid = gid - 786432u;
        const int e = fid & 7, l = (fid >> 3) & 63;
        const int rest = fid >> 9;             // 0..511
        const int kt = rest & 7, q = rest >> 3;
        const int g = q & 3, w2 = (q >> 2) & 3, c2 = q >> 4;
        const int k = kt * 32 + (l >> 4) * 8 + e;
        const int n = g * 256 + c2 * 64 + w2 * 16 + (l & 15);
        ((unsigned short*)(ws + OFF_WL1))[fid] =
            f2b(eW1[(size_t)k * 1024 + n] + eU1[(size_t)k * 1024 + n]);
    } else if (gid < 1310720u) {               // WDEC = dU + oW@dW, KT=8
        const unsigned fid = gid - 1048576u;
        const int e = fid & 7, l = (fid >> 3) & 63;
        const int rest = fid >> 9;
        const int kt = rest & 7, q = rest >> 3;
        const int g = q & 3, w2 = (q >> 2) & 3, c2 = q >> 4;
        const int k = kt * 32 + (l >> 4) * 8 + e;
        const int n = g * 256 + c2 * 64 + w2 * 16 + (l & 15);
        float s = dU[(size_t)k * 1024 + n];
        for (int d = 0; d < 128; ++d)
            s += oW[(size_t)k * 128 + d] * dW[(size_t)d * 1024 + n];
        ((unsigned short*)(ws + OFF_WDEC))[fid] = f2b(s);
    } else if (gid < 1343488u) {               // WOUT = oW (256x128), KT=8
        const unsigned fid = gid - 1310720u;
        const int e = fid & 7, l = (fid >> 3) & 63;
        const int rest = fid >> 9;             // 0..63
        const int kt = rest & 7, nt = rest >> 3;
        const int k = kt * 32 + (l >> 4) * 8 + e;
        const int d = nt * 16 + (l & 15);
        ((unsigned short*)(ws + OFF_WOUT))[fid] = f2b(oW[(size_t)k * 128 + d]);
    } else if (gid < 1344512u) {               // BDR = db + ob@dW
        const int n = (int)(gid - 1343488u);
        float s = db[n];
        for (int d = 0; d < 128; ++d)
            s += ob[d] * dW[(size_t)d * 1024 + n];
        ((float*)(ws + OFF_BDR))[n] = s;
    } else if (gid < 1348608u) {               // zero flags (every launch)
        ((unsigned int*)(ws + OFF_FLAG))[gid - 1344512u] = 0u;
    }
}

// ---------------- main: 128 persistent blocks, weights in VGPRs ------------
// Block (r = bid&31, c = bid>>5): batch rows [r*16, r*16+16), h cols
// [c*64, (c+1)*64).  4 waves; wave w owns h cols [c*64+w*16, +16) x 4 gates
// (gate-planar -> all 4 gates of a column land in the same lane; LSTM
// epilogue + c-state fully in registers).  Per phase the 4 sibling blocks
// exchange their 16x64 bf16 h-chunk via LLC (double-buffered by phase
// parity; release = threadfence+agent-atomic flag, acquire = threadfence).
// Depth-2 buffering is safe: posting phase P+1 implies having consumed P.

template <int KT>
__device__ __forceinline__ void mfma4(const unsigned short* __restrict__ aptr,
                                      const v8s* __restrict__ wreg, v4f acc[4])
{
    #pragma unroll
    for (int kt = 0; kt < KT; ++kt) {
        const v8s a = *(const v8s*)(aptr + kt * 32);
        #pragma unroll
        for (int g = 0; g < 4; ++g)
            acc[g] = __builtin_amdgcn_mfma_f32_16x16x32_bf16(a, wreg[g * KT + kt], acc[g], 0, 0, 0);
    }
}

#define ACC_BIAS(B)                                                          \
    do {                                                                     \
        _Pragma("unroll")                                                    \
        for (int g = 0; g < 4; ++g) {                                        \
            acc[g][0] = (B)[g]; acc[g][1] = (B)[g];                          \
            acc[g][2] = (B)[g]; acc[g][3] = (B)[g];                          \
        }                                                                    \
    } while (0)

// epilogue: all 4 gates in-lane; c in registers; h chunk -> hbuf[P&1]
#define EPILOGUE()                                                           \
    do {                                                                     \
        unsigned short* hdst_ = hb + (P & 1) * 4096;                         \
        _Pragma("unroll")                                                    \
        for (int reg = 0; reg < 4; ++reg) {                                  \
            const float ii = sig(acc[0][reg]);                               \
            const float ff = sig(acc[1][reg]);                               \
            const float gg = fmaxf(acc[2][reg], 0.f);                        \
            const float oo = sig(acc[3][reg]);                               \
            const float cc = ff * creg[reg] + ii * gg;                       \
            creg[reg] = cc;                                                  \
            hdst_[(kg * 4 + reg) * 256 + j] = f2b(oo * fmaxf(cc, 0.f));      \
        }                                                                    \
    } while (0)

// post own flag, wait 3 peers, stage full 16x256 h into Abuf cols 128..383
#define EXCHANGE_WAIT()                                                      \
    do {                                                                     \
        __syncthreads();          /* drains all waves' h stores to L2 */     \
        if (tid == 0) {                                                      \
            __threadfence();      /* L2 writeback -> LLC (release) */        \
            __hip_atomic_store(flagOwn, (unsigned)P, __ATOMIC_RELAXED,       \
                               __HIP_MEMORY_SCOPE_AGENT);                    \
        }                                                                    \
        if (tid < 3) {                                                       \
            const int peer_ = tid + (tid >= c ? 1 : 0);                      \
            unsigned int* fp_ = flagB + (r * 4 + peer_) * 32;                \
            while (__hip_atomic_load(fp_, __ATOMIC_RELAXED,                  \
                                     __HIP_MEMORY_SCOPE_AGENT) < (unsigned)P)\
                __builtin_amdgcn_s_sleep(1);                                 \
        }                                                                    \
        __syncthreads();                                                     \
        __threadfence();          /* invalidate L1/L2 (acquire) */           \
        {                                                                    \
            const unsigned short* hsrc_ = hb + (P & 1) * 4096;               \
            const int seg_ = tid & 15;                                       \
            const v8s h0_ = *(const v8s*)(hsrc_ + xrow * 256 + seg_ * 16);   \
            const v8s h1_ = *(const v8s*)(hsrc_ + xrow * 256 + seg_ * 16 + 8);\
            *(v8s*)&Abuf[xrow * AST + 128 + seg_ * 16]     = h0_;            \
            *(v8s*)&Abuf[xrow * AST + 128 + seg_ * 16 + 8] = h1_;            \
        }                                                                    \
    } while (0)

__global__ void __launch_bounds__(256, 1) lstm_main(
    const float* __restrict__ enc_in, const float* __restrict__ dec_in,
    const float* __restrict__ eb0, const float* __restrict__ eb1,
    const float* __restrict__ db,  const float* __restrict__ dW,
    const float* __restrict__ dU,  const float* __restrict__ ob,
    char* __restrict__ ws, float* __restrict__ out)
{
    __shared__ __align__(16) unsigned short Abuf[16 * AST];

    const int tid = threadIdx.x;
    const int w   = tid >> 6, l = tid & 63;
    const int cn  = l & 15,  kg = l >> 4;
    const int r   = blockIdx.x & 31, c = blockIdx.x >> 5;  // group, chunk
    const int m0  = r * 16;
    const int j   = c * 64 + w * 16 + cn;                  // absolute h col

    const int xrow = tid >> 4, xc8 = (tid & 15) * 8;       // staging coords

    const v8s* WL0p = (const v8s*)(ws + OFF_WL0)  + (size_t)(c * 4 + w) * 3072 + l;
    const v8s* WL1p = (const v8s*)(ws + OFF_WL1)  + (size_t)(c * 4 + w) * 2048 + l;
    const v8s* WDEp = (const v8s*)(ws + OFF_WDEC) + (size_t)(c * 4 + w) * 2048 + l;
    const v8s* WOUp = (const v8s*)(ws + OFF_WOUT) + (size_t)(c * 2 + w) * 512  + l;

    unsigned short* hb = (unsigned short*)(ws + OFF_HBUF) + (size_t)r * 8192;
    unsigned int* flagB   = (unsigned int*)(ws + OFF_FLAG);
    unsigned int* flagOwn = flagB + (r * 4 + c) * 32;

    // resident weights
    v8s wl0[48], wl1[32];
    #pragma unroll
    for (int i = 0; i < 48; ++i) wl0[i] = WL0p[i * 64];
    #pragma unroll
    for (int i = 0; i < 32; ++i) wl1[i] = WL1p[i * 64];

    float bl0[4], bl1[4], bde[4];
    #pragma unroll
    for (int g = 0; g < 4; ++g) {
        bl0[g] = eb0[g * 256 + j];
        bl1[g] = eb1[g * 256 + j];
        bde[g] = ((const float*)(ws + OFF_BDR))[g * 256 + j];
    }

    v4f creg = {0.f, 0.f, 0.f, 0.f};
    v4f acc[4];

    // init LDS (h section = 0), stage x_0
    for (int i = tid; i < 16 * AST / 2; i += 256) ((unsigned int*)Abuf)[i] = 0u;
    __syncthreads();
    {
        const float* s = enc_in + (size_t)(m0 + xrow) * RS + xc8;
        const float4 a = *(const float4*)s, b = *(const float4*)(s + 4);
        const unsigned u0 = ((unsigned)f2b(a.y) << 16) | f2b(a.x);
        const unsigned u1 = ((unsigned)f2b(a.w) << 16) | f2b(a.z);
        const unsigned u2 = ((unsigned)f2b(b.y) << 16) | f2b(b.x);
        const unsigned u3 = ((unsigned)f2b(b.w) << 16) | f2b(b.z);
        uint4 uu = {u0, u1, u2, u3};
        *(uint4*)&Abuf[xrow * AST + xc8] = uu;
    }
    __syncthreads();

    int P = 0;

    // ---------------- encoder ----------------
    for (int t = 0; t < T_; ++t) {
        // prefetch x_{t+1} (consumed at L0's staging point)
        const int tn = (t + 1 < T_) ? t + 1 : t;
        const float* xs = enc_in + (size_t)(m0 + xrow) * RS + (size_t)tn * 128 + xc8;
        const float4 xa = *(const float4*)xs;
        const float4 xb = *(const float4*)(xs + 4);

        // L0: z = [x_t | h2] @ WL0
        ACC_BIAS(bl0);
        mfma4<12>(Abuf + cn * AST + kg * 8, wl0, acc);
        ++P;
        EPILOGUE();              // -> h1 chunk
        EXCHANGE_WAIT();         // h1 full -> Abuf+128
        {   // write x_{t+1} into cols 0..127 (x_t dead after L0)
            const unsigned u0 = ((unsigned)f2b(xa.y) << 16) | f2b(xa.x);
            const unsigned u1 = ((unsigned)f2b(xa.w) << 16) | f2b(xa.z);
            const unsigned u2 = ((unsigned)f2b(xb.y) << 16) | f2b(xb.x);
            const unsigned u3 = ((unsigned)f2b(xb.w) << 16) | f2b(xb.z);
            uint4 uu = {u0, u1, u2, u3};
            *(uint4*)&Abuf[xrow * AST + xc8] = uu;
        }
        __syncthreads();

        // L1: z = h1 @ (W1+U1)
        ACC_BIAS(bl1);
        mfma4<8>(Abuf + 128 + cn * AST + kg * 8, wl1, acc);
        ++P;
        EPILOGUE();              // -> h2 chunk
        EXCHANGE_WAIT();         // h2 full -> Abuf+128
        __syncthreads();
    }

    // ---------------- decoder ----------------
    #pragma unroll
    for (int i = 0; i < 32; ++i) wl1[i] = WDEp[i * 64];   // dU + oW@dW
    v8s wout[8];
    if (w < 2) {
        #pragma unroll
        for (int i = 0; i < 8; ++i) wout[i] = WOUp[i * 64];
    }
    const float obv = (w < 2) ? ob[(c * 2 + w) * 16 + cn] : 0.f;
    float bd0[4];
    #pragma unroll
    for (int g = 0; g < 4; ++g) bd0[g] = db[g * 256 + j];

    {   // stage dec x0 into cols 0..127 (h section already = h_enc)
        const float* s = dec_in + (size_t)(m0 + xrow) * RS + xc8;
        const float4 a = *(const float4*)s, b = *(const float4*)(s + 4);
        const unsigned u0 = ((unsigned)f2b(a.y) << 16) | f2b(a.x);
        const unsigned u1 = ((unsigned)f2b(a.w) << 16) | f2b(a.z);
        const unsigned u2 = ((unsigned)f2b(b.y) << 16) | f2b(b.x);
        const unsigned u3 = ((unsigned)f2b(b.w) << 16) | f2b(b.z);
        uint4 uu = {u0, u1, u2, u3};
        *(uint4*)&Abuf[xrow * AST + xc8] = uu;
    }
    __syncthreads();

    for (int t = 0; t < T_; ++t) {
        if (t == 0) {
            // z = [x0 | h_enc] @ [dW;dU]; B streamed once from raw f32
            ACC_BIAS(bd0);
            const unsigned short* aptr = Abuf + cn * AST + kg * 8;
            #pragma unroll
            for (int kt = 0; kt < 12; ++kt) {
                const v8s a = *(const v8s*)(aptr + kt * 32);
                #pragma unroll
                for (int g = 0; g < 4; ++g) {
                    const int n = g * 256 + j;
                    v8s bv;
                    #pragma unroll
                    for (int e = 0; e < 8; ++e) {
                        const int k = kt * 32 + kg * 8 + e;
                        const float v = (k < 128)
                            ? dW[(size_t)k * 1024 + n]
                            : dU[(size_t)(k - 128) * 1024 + n];
                        bv[e] = (short)f2b(v);
                    }
                    acc[g] = __builtin_amdgcn_mfma_f32_16x16x32_bf16(a, bv, acc[g], 0, 0, 0);
                }
            }
        } else {
            // z = h_d @ (dU + oW@dW)  (input fold: inp(t) = out(t-1))
            ACC_BIAS(bde);
            mfma4<8>(Abuf + 128 + cn * AST + kg * 8, wl1, acc);
        }
        ++P;
        EPILOGUE();              // -> h_d chunk
        EXCHANGE_WAIT();         // h_d full -> Abuf+128
        __syncthreads();

        // out(t) = h_d(t) @ oW + ob   (waves 0-1, d-chunk [c*32, c*32+32))
        if (w < 2) {
            const unsigned short* ap = Abuf + 128 + cn * AST + kg * 8;
            v4f oc = {obv, obv, obv, obv};
            #pragma unroll
            for (int kt = 0; kt < 8; ++kt)
                oc = __builtin_amdgcn_mfma_f32_16x16x32_bf16(
                    *(const v8s*)(ap + kt * 32), wout[kt], oc, 0, 0, 0);
            const int d = (c * 2 + w) * 16 + cn;
            float* op = out + (size_t)(m0 + kg * 4) * RS + (size_t)t * 128 + d;
            #pragma unroll
            for (int reg = 0; reg < 4; ++reg) op[(size_t)reg * RS] = oc[reg];
        }
    }
}

extern "C" void kernel_launch(void* const* d_in, const int* in_sizes, int n_in,
                              void* d_out, int out_size, void* d_ws, size_t ws_size,
                              hipStream_t stream)
{
    const float* enc_in = (const float*)d_in[0];
    const float* dec_in = (const float*)d_in[1];
    const float* eW0 = (const float*)d_in[2];
    const float* eU0 = (const float*)d_in[3];
    const float* eb0 = (const float*)d_in[4];
    const float* eW1 = (const float*)d_in[5];
    const float* eU1 = (const float*)d_in[6];
    const float* eb1 = (const float*)d_in[7];
    const float* dW  = (const float*)d_in[8];
    const float* dU  = (const float*)d_in[9];
    const float* db  = (const float*)d_in[10];
    const float* oW  = (const float*)d_in[11];
    const float* ob  = (const float*)d_in[12];
    char* ws = (char*)d_ws;
    float* out = (float*)d_out;

    prep_kernel<<<5268, 256, 0, stream>>>(eW0, eU0, eW1, eU1, dW, dU, db, oW, ob, ws);
    lstm_main<<<128, 256, 0, stream>>>(enc_in, dec_in, eb0, eb1, db, dW, dU, ob, ws, out);
}

// Round 2
// 6429.787 us; speedup vs baseline: 2.9445x; 2.9445x over previous
//
#include <hip/hip_runtime.h>
#include <hip/hip_bf16.h>

typedef __attribute__((ext_vector_type(8))) short v8s;
typedef __attribute__((ext_vector_type(4))) float v4f;

constexpr int T_  = 512;
constexpr int RS  = 65536;   // fp32 row stride of enc/dec/out: T*D
constexpr int AST = 392;     // Abuf row stride in shorts (384 cols + 8 pad)

// ws offsets (bytes)
constexpr size_t OFF_WL0  = 0;         // enc L0 [eW0;eU0] frag-packed bf16, 786432 sh
constexpr size_t OFF_WL1  = 1572864;   // enc L1 (W1+U1) frag-packed bf16, 262144 sh
constexpr size_t OFF_WDEC = 2097152;   // dec (dU + oW@dW) frag-packed bf16, 262144 sh
constexpr size_t OFF_WOUT = 2621440;   // oW frag-packed bf16, 32768 sh
constexpr size_t OFF_BDR  = 2686976;   // db + ob@dW, 1024 f32
constexpr size_t OFF_HBUF = 2691072;   // [32 grp][4 chunk][2 parity][512 qword] = 1 MiB
// total 3739648 bytes

__device__ __forceinline__ unsigned short f2b(float x) {
    __hip_bfloat16 h = __float2bfloat16(x);
    return *(unsigned short*)&h;
}
__device__ __forceinline__ float sig(float x) { return 1.f / (1.f + __expf(-x)); }

// ---------------- prep: repack fp32 weights into per-(chunk,wave,gate) -----
// Frag layout (16x16x32): lane l, elem e of frag (g,kt) holds
// B[k = kt*32 + (l>>4)*8 + e][n = g*256 + c*64 + w*16 + (l&15)]  (gate-planar).
__global__ void __launch_bounds__(256) prep_kernel(
    const float* __restrict__ eW0, const float* __restrict__ eU0,
    const float* __restrict__ eW1, const float* __restrict__ eU1,
    const float* __restrict__ dW,  const float* __restrict__ dU,
    const float* __restrict__ db,
    const float* __restrict__ oW,  const float* __restrict__ ob,
    char* __restrict__ ws)
{
    const unsigned gid = blockIdx.x * 256u + threadIdx.x;

    if (gid < 786432u) {                       // WL0 = [eW0;eU0], KT=12
        const unsigned fid = gid;
        const int e = fid & 7, l = (fid >> 3) & 63;
        const int rest = fid >> 9;             // 0..767
        const int kt = rest % 12, q = rest / 12;
        const int g = q & 3, w2 = (q >> 2) & 3, c2 = q >> 4;
        const int k = kt * 32 + (l >> 4) * 8 + e;
        const int n = g * 256 + c2 * 64 + w2 * 16 + (l & 15);
        const float v = (k < 128) ? eW0[(size_t)k * 1024 + n]
                                  : eU0[(size_t)(k - 128) * 1024 + n];
        ((unsigned short*)(ws + OFF_WL0))[fid] = f2b(v);
    } else if (gid < 1048576u) {               // WL1 = W1+U1, KT=8
        const unsigned fid = gid - 786432u;
        const int e = fid & 7, l = (fid >> 3) & 63;
        const int rest = fid >> 9;             // 0..511
        const int kt = rest & 7, q = rest >> 3;
        const int g = q & 3, w2 = (q >> 2) & 3, c2 = q >> 4;
        const int k = kt * 32 + (l >> 4) * 8 + e;
        const int n = g * 256 + c2 * 64 + w2 * 16 + (l & 15);
        ((unsigned short*)(ws + OFF_WL1))[fid] =
            f2b(eW1[(size_t)k * 1024 + n] + eU1[(size_t)k * 1024 + n]);
    } else if (gid < 1310720u) {               // WDEC = dU + oW@dW, KT=8
        const unsigned fid = gid - 1048576u;
        const int e = fid & 7, l = (fid >> 3) & 63;
        const int rest = fid >> 9;
        const int kt = rest & 7, q = rest >> 3;
        const int g = q & 3, w2 = (q >> 2) & 3, c2 = q >> 4;
        const int k = kt * 32 + (l >> 4) * 8 + e;
        const int n = g * 256 + c2 * 64 + w2 * 16 + (l & 15);
        float s = dU[(size_t)k * 1024 + n];
        for (int d = 0; d < 128; ++d)
            s += oW[(size_t)k * 128 + d] * dW[(size_t)d * 1024 + n];
        ((unsigned short*)(ws + OFF_WDEC))[fid] = f2b(s);
    } else if (gid < 1343488u) {               // WOUT = oW (256x128), KT=8
        const unsigned fid = gid - 1310720u;
        const int e = fid & 7, l = (fid >> 3) & 63;
        const int rest = fid >> 9;             // 0..63
        const int kt = rest & 7, nt = rest >> 3;
        const int k = kt * 32 + (l >> 4) * 8 + e;
        const int d = nt * 16 + (l & 15);
        ((unsigned short*)(ws + OFF_WOUT))[fid] = f2b(oW[(size_t)k * 128 + d]);
    } else if (gid < 1344512u) {               // BDR = db + ob@dW
        const int n = (int)(gid - 1343488u);
        float s = db[n];
        for (int d = 0; d < 128; ++d)
            s += ob[d] * dW[(size_t)d * 1024 + n];
        ((float*)(ws + OFF_BDR))[n] = s;
    } else if (gid < 1475584u) {               // zero hbuf tags (every launch)
        ((unsigned long long*)(ws + OFF_HBUF))[gid - 1344512u] = 0ull;
    }
}

// ---------------- main: 128 persistent blocks, 8 waves, K-split ------------
// Block (r = bid&31, c = bid>>5): batch rows [r*16,+16), h cols [c*64,+64).
// Waves 0-3 ("front", cw=w): low K-half weights + bias + c-state + epilogue.
// Waves 4-7 ("back", cw=w-4): high K-half weights; partial acc -> Comb LDS;
// decoder out-proj on waves 4,5.  Exchange between the 4 sibling blocks is
// fence-free: each 8-B qword = {h[2rp][col], h[2rp+1][col], tag=P} stored as
// one relaxed agent-scope atomic (self-validating; per-qword atomicity is the
// only ordering needed).  Depth-2 parity buffers: producing P implies peers
// consumed P-2 (data dependency), so overwrite is safe.  Tags monotonic.

template <int KTH>
__device__ __forceinline__ void mfma4h(const unsigned short* __restrict__ aptr,
                                       const v8s* __restrict__ wreg, v4f acc[4])
{
    #pragma unroll
    for (int kt = 0; kt < KTH; ++kt) {
        const v8s a = *(const v8s*)(aptr + kt * 32);
        #pragma unroll
        for (int g = 0; g < 4; ++g)
            acc[g] = __builtin_amdgcn_mfma_f32_16x16x32_bf16(a, wreg[g * KTH + kt], acc[g], 0, 0, 0);
    }
}

#define ACCI(B)                                                              \
    do {                                                                     \
        _Pragma("unroll")                                                    \
        for (int g = 0; g < 4; ++g) {                                        \
            acc[g][0] = (B)[g]; acc[g][1] = (B)[g];                          \
            acc[g][2] = (B)[g]; acc[g][3] = (B)[g];                          \
        }                                                                    \
    } while (0)

#define COMB_WRITE()                                                         \
    do {                                                                     \
        _Pragma("unroll")                                                    \
        for (int g = 0; g < 4; ++g) *(v4f*)(cmb + g * 1024) = acc[g];        \
    } while (0)

// front only: combine halves, LSTM epilogue (c in regs), publish h chunk
#define EPI_PUBLISH()                                                        \
    do {                                                                     \
        _Pragma("unroll")                                                    \
        for (int g = 0; g < 4; ++g) acc[g] += *(const v4f*)(cmb + g * 1024); \
        unsigned short hv[4];                                                \
        _Pragma("unroll")                                                    \
        for (int reg = 0; reg < 4; ++reg) {                                  \
            const float ii = sig(acc[0][reg]);                               \
            const float ff = sig(acc[1][reg]);                               \
            const float gg = fmaxf(acc[2][reg], 0.f);                        \
            const float oo = sig(acc[3][reg]);                               \
            const float cc = ff * creg[reg] + ii * gg;                       \
            creg[reg] = cc;                                                  \
            hv[reg] = f2b(oo * fmaxf(cc, 0.f));                              \
        }                                                                    \
        unsigned long long* own_ = hbq + ((size_t)((r * 4 + c) * 2 + (P & 1))) * 512; \
        const int lc_ = cw * 16 + cn;                                        \
        const unsigned long long tg_ = ((unsigned long long)(unsigned)P) << 32; \
        __hip_atomic_store(own_ + (kg * 2) * 64 + lc_,                       \
            tg_ | (unsigned)hv[0] | ((unsigned)hv[1] << 16),                 \
            __ATOMIC_RELAXED, __HIP_MEMORY_SCOPE_AGENT);                     \
        __hip_atomic_store(own_ + (kg * 2 + 1) * 64 + lc_,                   \
            tg_ | (unsigned)hv[2] | ((unsigned)hv[3] << 16),                 \
            __ATOMIC_RELAXED, __HIP_MEMORY_SCOPE_AGENT);                     \
        Abuf[(kg * 4 + 0) * AST + 128 + j] = hv[0];                          \
        Abuf[(kg * 4 + 1) * AST + 128 + j] = hv[1];                          \
        Abuf[(kg * 4 + 2) * AST + 128 + j] = hv[2];                          \
        Abuf[(kg * 4 + 3) * AST + 128 + j] = hv[3];                          \
    } while (0)

#define PLD(qp) __hip_atomic_load((qp), __ATOMIC_RELAXED, __HIP_MEMORY_SCOPE_AGENT)

// all 512 threads: poll 3 peers' qword[tid], stage into Abuf h-region
#define POLL_STAGE()                                                         \
    do {                                                                     \
        const int par_ = P & 1;                                              \
        const int cpA_ = (c == 0) ? 1 : 0;                                   \
        const int cpB_ = (c <= 1) ? 2 : 1;                                   \
        const int cpC_ = (c <= 2) ? 3 : 2;                                   \
        const unsigned long long* qp0_ = hbq + ((size_t)((r * 4 + cpA_) * 2 + par_)) * 512 + tid; \
        const unsigned long long* qp1_ = hbq + ((size_t)((r * 4 + cpB_) * 2 + par_)) * 512 + tid; \
        const unsigned long long* qp2_ = hbq + ((size_t)((r * 4 + cpC_) * 2 + par_)) * 512 + tid; \
        unsigned long long q0_ = PLD(qp0_), q1_ = PLD(qp1_), q2_ = PLD(qp2_);\
        while ((unsigned)(q0_ >> 32) != (unsigned)P) q0_ = PLD(qp0_);        \
        while ((unsigned)(q1_ >> 32) != (unsigned)P) q1_ = PLD(qp1_);        \
        while ((unsigned)(q2_ >> 32) != (unsigned)P) q2_ = PLD(qp2_);        \
        const int rr_ = (tid >> 6) * 2, lcc_ = tid & 63;                     \
        Abuf[rr_ * AST + 128 + cpA_ * 64 + lcc_]       = (unsigned short)q0_; \
        Abuf[(rr_ + 1) * AST + 128 + cpA_ * 64 + lcc_] = (unsigned short)(q0_ >> 16); \
        Abuf[rr_ * AST + 128 + cpB_ * 64 + lcc_]       = (unsigned short)q1_; \
        Abuf[(rr_ + 1) * AST + 128 + cpB_ * 64 + lcc_] = (unsigned short)(q1_ >> 16); \
        Abuf[rr_ * AST + 128 + cpC_ * 64 + lcc_]       = (unsigned short)q2_; \
        Abuf[(rr_ + 1) * AST + 128 + cpC_ * 64 + lcc_] = (unsigned short)(q2_ >> 16); \
    } while (0)

#define XSTAGE(v)                                                            \
    do {                                                                     \
        const unsigned u0_ = ((unsigned)f2b((v).y) << 16) | f2b((v).x);      \
        const unsigned u1_ = ((unsigned)f2b((v).w) << 16) | f2b((v).z);      \
        uint2 uu_; uu_.x = u0_; uu_.y = u1_;                                 \
        *(uint2*)&Abuf[xr * AST + xq] = uu_;                                 \
    } while (0)

__global__ void __launch_bounds__(512, 2) lstm_main(
    const float* __restrict__ enc_in, const float* __restrict__ dec_in,
    const float* __restrict__ eb0, const float* __restrict__ eb1,
    const float* __restrict__ db,  const float* __restrict__ dW,
    const float* __restrict__ dU,  const float* __restrict__ ob,
    char* __restrict__ ws, float* __restrict__ out)
{
    __shared__ __align__(16) unsigned short Abuf[16 * AST];
    __shared__ __align__(16) float Comb[4 * 4 * 64 * 4];   // [g][cw][lane][4]

    const int tid = threadIdx.x;
    const int w = tid >> 6, l = tid & 63;
    const int cn = l & 15, kg = l >> 4;
    const bool front = (w < 4);
    const int cw = w & 3;
    const int r = blockIdx.x & 31, c = blockIdx.x >> 5;
    const int m0 = r * 16;
    const int j = c * 64 + cw * 16 + cn;
    const int xr = tid >> 5, xq = (tid & 31) * 4;

    const v8s* WL0p = (const v8s*)(ws + OFF_WL0)  + (size_t)(c * 4 + cw) * 3072 + l;
    const v8s* WL1p = (const v8s*)(ws + OFF_WL1)  + (size_t)(c * 4 + cw) * 2048 + l;
    const v8s* WDEp = (const v8s*)(ws + OFF_WDEC) + (size_t)(c * 4 + cw) * 2048 + l;

    unsigned long long* hbq = (unsigned long long*)(ws + OFF_HBUF);

    const int h0off = front ? 0 : 6;   // L0 kt offset (KT=12 split 6+6)
    const int h1off = front ? 0 : 4;   // L1/dec kt offset (KT=8 split 4+4)

    // resident weight halves (160 VGPRs)
    v8s wl0[24], wl1[16];
    #pragma unroll
    for (int g = 0; g < 4; ++g)
        #pragma unroll
        for (int k2 = 0; k2 < 6; ++k2)
            wl0[g * 6 + k2] = WL0p[(g * 12 + k2 + h0off) * 64];
    #pragma unroll
    for (int g = 0; g < 4; ++g)
        #pragma unroll
        for (int k2 = 0; k2 < 4; ++k2)
            wl1[g * 4 + k2] = WL1p[(g * 8 + k2 + h1off) * 64];

    float bl0[4], bl1[4];
    #pragma unroll
    for (int g = 0; g < 4; ++g) {
        bl0[g] = front ? eb0[g * 256 + j] : 0.f;
        bl1[g] = front ? eb1[g * 256 + j] : 0.f;
    }

    const unsigned short* apL0 = Abuf + cn * AST + kg * 8 + (front ? 0 : 192);
    const unsigned short* apL1 = Abuf + 128 + cn * AST + kg * 8 + (front ? 0 : 128);
    float* cmb = Comb + (cw * 64 + l) * 4;

    v4f creg = {0.f, 0.f, 0.f, 0.f};
    v4f acc[4];
    int P = 0;

    // init LDS, stage x_0
    for (int i = tid; i < 16 * AST / 2; i += 512) ((unsigned int*)Abuf)[i] = 0u;
    __syncthreads();
    { const float4 v = *(const float4*)(enc_in + (size_t)(m0 + xr) * RS + xq); XSTAGE(v); }
    __syncthreads();

    // ---------------- encoder ----------------
    #pragma unroll 1
    for (int t = 0; t < T_; ++t) {
        const int tn = (t + 1 < T_) ? t + 1 : t;
        const float4 xv = *(const float4*)(enc_in + (size_t)(m0 + xr) * RS
                                           + (size_t)tn * 128 + xq);

        // L0: z = [x_t | h2] @ WL0
        ACCI(bl0);
        mfma4h<6>(apL0, wl0, acc);
        ++P;
        if (!front) COMB_WRITE();
        __syncthreads();
        if (front) EPI_PUBLISH();        // -> h1 chunk
        XSTAGE(xv);                      // x_t dead after L0 MFMA
        POLL_STAGE();                    // h1 full -> Abuf h-region
        __syncthreads();

        // L1: z = h1 @ (W1+U1)
        ACCI(bl1);
        mfma4h<4>(apL1, wl1, acc);
        ++P;
        if (!front) COMB_WRITE();
        __syncthreads();
        if (front) EPI_PUBLISH();        // -> h2 chunk
        POLL_STAGE();
        __syncthreads();
    }

    // ---------------- decoder ----------------
    #pragma unroll
    for (int g = 0; g < 4; ++g)
        #pragma unroll
        for (int k2 = 0; k2 < 4; ++k2)
            wl1[g * 4 + k2] = WDEp[(g * 8 + k2 + h1off) * 64];   // dU + oW@dW

    v8s wout[8];
    const int wo = w - 4;
    if (wo == 0 || wo == 1) {
        const v8s* WOUp = (const v8s*)(ws + OFF_WOUT) + (size_t)(c * 2 + wo) * 512 + l;
        #pragma unroll
        for (int kt = 0; kt < 8; ++kt) wout[kt] = WOUp[kt * 64];
    }
    const float obv = (wo == 0 || wo == 1) ? ob[(c * 2 + wo) * 16 + cn] : 0.f;

    float bd0[4], bde[4];
    #pragma unroll
    for (int g = 0; g < 4; ++g) {
        bd0[g] = front ? db[g * 256 + j] : 0.f;
        bde[g] = front ? ((const float*)(ws + OFF_BDR))[g * 256 + j] : 0.f;
    }

    { const float4 v = *(const float4*)(dec_in + (size_t)(m0 + xr) * RS + xq); XSTAGE(v); }
    __syncthreads();

    #pragma unroll 1
    for (int t = 0; t < T_; ++t) {
        if (t == 0) {
            // z = [x0 | h_enc] @ [dW;dU]; B built once from raw f32
            ACCI(bd0);
            const int ktb = front ? 0 : 6;
            #pragma unroll
            for (int kt2 = 0; kt2 < 6; ++kt2) {
                const v8s a = *(const v8s*)(apL0 + kt2 * 32);
                #pragma unroll
                for (int g = 0; g < 4; ++g) {
                    const int n = g * 256 + j;
                    v8s bv;
                    #pragma unroll
                    for (int e = 0; e < 8; ++e) {
                        const int k = (kt2 + ktb) * 32 + kg * 8 + e;
                        const float v = (k < 128)
                            ? dW[(size_t)k * 1024 + n]
                            : dU[(size_t)(k - 128) * 1024 + n];
                        bv[e] = (short)f2b(v);
                    }
                    acc[g] = __builtin_amdgcn_mfma_f32_16x16x32_bf16(a, bv, acc[g], 0, 0, 0);
                }
            }
        } else {
            // z = h_d @ (dU + oW@dW)   (input fold: inp(t) = out(t-1))
            ACCI(bde);
            mfma4h<4>(apL1, wl1, acc);
        }
        ++P;
        if (!front) COMB_WRITE();
        __syncthreads();
        if (front) EPI_PUBLISH();        // -> h_d chunk
        POLL_STAGE();
        __syncthreads();

        // out(t) = h_d(t) @ oW + ob  (waves 4,5; d-chunk [c*32,+32))
        if (wo == 0 || wo == 1) {
            const unsigned short* apO = Abuf + 128 + cn * AST + kg * 8;
            v4f oc = {obv, obv, obv, obv};
            #pragma unroll
            for (int kt = 0; kt < 8; ++kt)
                oc = __builtin_amdgcn_mfma_f32_16x16x32_bf16(
                    *(const v8s*)(apO + kt * 32), wout[kt], oc, 0, 0, 0);
            const int d = (c * 2 + wo) * 16 + cn;
            float* op = out + (size_t)(m0 + kg * 4) * RS + (size_t)t * 128 + d;
            #pragma unroll
            for (int reg = 0; reg < 4; ++reg) op[(size_t)reg * RS] = oc[reg];
        }
    }
}

extern "C" void kernel_launch(void* const* d_in, const int* in_sizes, int n_in,
                              void* d_out, int out_size, void* d_ws, size_t ws_size,
                              hipStream_t stream)
{
    const float* enc_in = (const float*)d_in[0];
    const float* dec_in = (const float*)d_in[1];
    const float* eW0 = (const float*)d_in[2];
    const float* eU0 = (const float*)d_in[3];
    const float* eb0 = (const float*)d_in[4];
    const float* eW1 = (const float*)d_in[5];
    const float* eU1 = (const float*)d_in[6];
    const float* eb1 = (const float*)d_in[7];
    const float* dW  = (const float*)d_in[8];
    const float* dU  = (const float*)d_in[9];
    const float* db  = (const float*)d_in[10];
    const float* oW  = (const float*)d_in[11];
    const float* ob  = (const float*)d_in[12];
    char* ws = (char*)d_ws;
    float* out = (float*)d_out;

    prep_kernel<<<5764, 256, 0, stream>>>(eW0, eU0, eW1, eU1, dW, dU, db, oW, ob, ws);
    lstm_main<<<128, 512, 0, stream>>>(enc_in, dec_in, eb0, eb1, db, dW, dU, ob, ws, out);
}